// Round 1
// baseline (804.529 us; speedup 1.0000x reference)
//
#include <hip/hip_runtime.h>
#include <hip/hip_bf16.h>
#include <stdint.h>

// Problem constants (N=32, D_IN=1024, H=2048, D_OUT=256)
#define NP     32
#define P_W1   2097152   // H*D_IN
#define P_B1   2048      // H
#define P_W2   524288    // D_OUT*H
#define P_B2   256       // D_OUT
#define OFFB1  2097152
#define OFFW2  2099200
#define OFFB2  2623488
#define P_TOT  2623744
#define EPS_F  0.1f
#define NCHUNK (P_TOT / 256)   // 10249 column-chunks of 256 for apply

typedef short  bf16x8 __attribute__((ext_vector_type(8)));
typedef float  f32x16 __attribute__((ext_vector_type(16)));

// f32 -> bf16 round-to-nearest-even (no NaN in this data; 3 VALU ops)
__device__ __forceinline__ short f2bf(float x) {
    uint32_t u = __builtin_bit_cast(uint32_t, x);
    u += 0x7fffu + ((u >> 16) & 1u);
    return (short)(u >> 16);
}

struct Seg { const float* p; int stride; int off; };

// theta is the virtual concat [W1 | b1 | W2 | b2] per particle. All segment
// boundaries are multiples of 256, so any 256-aligned chunk stays in one segment.
__device__ __forceinline__ Seg seg_of(const float* W1, const float* b1,
                                      const float* W2, const float* b2, int pbase) {
    Seg s;
    if (pbase < OFFB1)      { s.p = W1; s.stride = P_W1; s.off = pbase; }
    else if (pbase < OFFW2) { s.p = b1; s.stride = P_B1; s.off = pbase - OFFB1; }
    else if (pbase < OFFB2) { s.p = W2; s.stride = P_W2; s.off = pbase - OFFW2; }
    else                    { s.p = b2; s.stride = P_B2; s.off = pbase - OFFB2; }
    return s;
}

__global__ void zero_kernel(float* __restrict__ G) {
    G[threadIdx.x] = 0.0f;   // <<<1,1024>>> zeros the 32x32 Gram accumulator
}

// G = theta @ theta^T via 32x32x16 bf16 MFMA. One wave covers the full 32x32
// tile; A and B fragments are the SAME registers (layout-permutation cancels).
// 2048 blocks (8192 waves, 8/SIMD target) instead of 256: gram is a pure
// HBM stream, needs wave parallelism to hide the ~900cy miss latency.
__global__ void __launch_bounds__(256)
gram_kernel(const float* __restrict__ W1, const float* __restrict__ b1,
            const float* __restrict__ W2, const float* __restrict__ b2,
            float* __restrict__ G) {
    const int lane   = threadIdx.x & 63;
    const int wave   = (blockIdx.x * 256 + threadIdx.x) >> 6;
    const int nwaves = gridDim.x * 4;
    const int row    = lane & 31;   // theta row this lane loads (= A.m and B.n)
    const int q      = lane >> 5;   // k half-select within fragment

    f32x16 acc;
    #pragma unroll
    for (int r = 0; r < 16; r++) acc[r] = 0.0f;

    for (int c = wave; c < P_TOT / 64; c += nwaves) {
        const int kb = c * 64;                       // 64-float superchunk = 4 MFMA k-chunks
        Seg s = seg_of(W1, b1, W2, b2, kb);
        const float* base = s.p + (size_t)row * s.stride + s.off + q * 8;

        #pragma unroll
        for (int cc = 0; cc < 4; cc++) {
            const float4 lo = *reinterpret_cast<const float4*>(base + cc * 16);
            const float4 hi = *reinterpret_cast<const float4*>(base + cc * 16 + 4);
            bf16x8 f;
            f[0] = f2bf(lo.x); f[1] = f2bf(lo.y); f[2] = f2bf(lo.z); f[3] = f2bf(lo.w);
            f[4] = f2bf(hi.x); f[5] = f2bf(hi.y); f[6] = f2bf(hi.z); f[7] = f2bf(hi.w);
            acc = __builtin_amdgcn_mfma_f32_32x32x16_bf16(f, f, acc, 0, 0, 0);
        }
    }

    // C/D layout (m74/m101): col = lane&31, row = (reg&3) + 8*(reg>>2) + 4*(lane>>5)
    #pragma unroll
    for (int r = 0; r < 16; r++) {
        const int orow = (r & 3) + 8 * (r >> 2) + 4 * q;
        atomicAdd(&G[orow * 32 + row], acc[r]);
    }
}

// M_full = I + M': the identity is folded in here so the apply kernel is a
// single 32x32 mat-vec with NO runtime-indexed register array (rule #20).
// M_full[i][j] = delta_ij + (EPS/n)*K[i][j]*[j>=1] - delta_ij * 3*EPS*S_i/n
__global__ void computeM_kernel(const float* __restrict__ G, float* __restrict__ Mp) {
    __shared__ float Ks[32][32];
    const int t = threadIdx.x;           // <<<1,1024>>>
    const int i = t >> 5, j = t & 31;
    const float sqi = G[i * 33];
    const float sqj = G[j * 33];
    const float d2  = fmaxf(sqi + sqj - 2.0f * G[i * 32 + j], 0.0f);
    const float K   = expf(-0.5f * d2);
    Ks[i][j] = K;
    __syncthreads();
    float S = 0.0f;
    for (int m = 1; m < 32; m++) S += Ks[i][m];
    float v = (j >= 1) ? (EPS_F / 32.0f) * K : 0.0f;
    if (i == j) v += 1.0f - (3.0f * EPS_F / 32.0f) * S;
    Mp[i * 32 + j] = v;
}

// out = M_full @ theta, pure f32 VALU (no MFMA: op is memory-bound, the 32x32
// mat-vec is only 5.4 GFLOP = 34 us at the 157 TF vector rate, hidden under
// the 672 MB stream). Each lane owns 4 consecutive columns (float4: 16 B/lane,
// 1 KB/wave-instr coalesced loads AND stores) and keeps all 32 particle rows
// in registers (128 VGPR). Mp rows are wave-uniform -> scalar s_loads.
__global__ void __launch_bounds__(256)
apply_kernel(const float* __restrict__ W1, const float* __restrict__ b1,
             const float* __restrict__ W2, const float* __restrict__ b2,
             const float* __restrict__ Mp, float* __restrict__ out) {
    const int lane   = threadIdx.x & 63;
    const int wave   = (blockIdx.x * 256 + threadIdx.x) >> 6;
    const int nwaves = gridDim.x * 4;

    for (int ch = wave; ch < NCHUNK; ch += nwaves) {
        const int pbase = ch * 256;                  // 256-col chunk, one segment
        Seg s = seg_of(W1, b1, W2, b2, pbase);
        const float* sp = s.p + s.off + lane * 4;
        const size_t str = (size_t)s.stride;

        float4 th[32];
        #pragma unroll
        for (int j = 0; j < 32; ++j)
            th[j] = *reinterpret_cast<const float4*>(sp + j * str);

        float* op = out + (size_t)pbase + lane * 4;
        #pragma unroll 1   // keep i-loop rolled: th[] stays the only big reg block
        for (int i = 0; i < 32; ++i) {
            const float* mrow = Mp + i * 32;         // uniform address -> s_load
            float ax = 0.f, ay = 0.f, az = 0.f, aw = 0.f;
            #pragma unroll
            for (int j = 0; j < 32; ++j) {
                const float m = mrow[j];
                ax = fmaf(m, th[j].x, ax);
                ay = fmaf(m, th[j].y, ay);
                az = fmaf(m, th[j].z, az);
                aw = fmaf(m, th[j].w, aw);
            }
            float4 o = { ax, ay, az, aw };
            *reinterpret_cast<float4*>(op + (size_t)i * P_TOT) = o;
        }
    }
}

extern "C" void kernel_launch(void* const* d_in, const int* in_sizes, int n_in,
                              void* d_out, int out_size, void* d_ws, size_t ws_size,
                              hipStream_t stream) {
    const float* W1 = (const float*)d_in[0];
    const float* b1 = (const float*)d_in[1];
    const float* W2 = (const float*)d_in[2];
    const float* b2 = (const float*)d_in[3];
    // d_in[4] (X) and d_in[5] (y) are unused by the reference computation.
    float* out = (float*)d_out;
    float* G   = (float*)d_ws;          // 1024 floats
    float* Mp  = G + 1024;              // 1024 floats

    zero_kernel<<<1, 1024, 0, stream>>>(G);
    gram_kernel<<<2048, 256, 0, stream>>>(W1, b1, W2, b2, G);
    computeM_kernel<<<1, 1024, 0, stream>>>(G, Mp);
    apply_kernel<<<1024, 256, 0, stream>>>(W1, b1, W2, b2, Mp, out);
}

// Round 2
// 744.744 us; speedup vs baseline: 1.0803x; 1.0803x over previous
//
#include <hip/hip_runtime.h>
#include <hip/hip_bf16.h>
#include <stdint.h>

// Problem constants (N=32, D_IN=1024, H=2048, D_OUT=256)
#define NP     32
#define P_W1   2097152   // H*D_IN
#define P_B1   2048      // H
#define P_W2   524288    // D_OUT*H
#define P_B2   256       // D_OUT
#define OFFB1  2097152
#define OFFW2  2099200
#define OFFB2  2623488
#define P_TOT  2623744
#define EPS_F  0.1f
#define NCHUNK (P_TOT / 256)   // 10249 column-chunks of 256

typedef short  bf16x8 __attribute__((ext_vector_type(8)));
typedef float  f32x16 __attribute__((ext_vector_type(16)));

// f32 -> bf16 round-to-nearest-even (no NaN in this data; 3 VALU ops)
__device__ __forceinline__ short f2bf(float x) {
    uint32_t u = __builtin_bit_cast(uint32_t, x);
    u += 0x7fffu + ((u >> 16) & 1u);
    return (short)(u >> 16);
}

struct Seg { const float* p; int stride; int off; };

// theta is the virtual concat [W1 | b1 | W2 | b2] per particle. All segment
// boundaries are multiples of 256, so any 256-aligned chunk stays in one segment.
__device__ __forceinline__ Seg seg_of(const float* W1, const float* b1,
                                      const float* W2, const float* b2, int pbase) {
    Seg s;
    if (pbase < OFFB1)      { s.p = W1; s.stride = P_W1; s.off = pbase; }
    else if (pbase < OFFW2) { s.p = b1; s.stride = P_B1; s.off = pbase - OFFB1; }
    else if (pbase < OFFB2) { s.p = W2; s.stride = P_W2; s.off = pbase - OFFW2; }
    else                    { s.p = b2; s.stride = P_B2; s.off = pbase - OFFB2; }
    return s;
}

__global__ void zero_kernel(float* __restrict__ G) {
    G[threadIdx.x] = 0.0f;   // <<<1,1024>>> zeros the 32x32 Gram accumulator
}

// G = theta @ theta^T via 32x32x16 bf16 MFMA, LDS-staged.
// Round-1 lesson: direct fragment-layout global loads scatter each float4
// instruction across 64 cache lines (row stride 8 MB) -> 0.9 TB/s, latency
// bound. Fix: per 256-col chunk, each wave loads 8 rows as ONE coalesced 1KB
// float4 instr per row, converts to bf16, writes a XOR-swizzled [32][256]
// bf16 LDS tile; fragments then come from LDS (swizzle kills the 32-way
// bank conflict of the stride-512B column read). T14: next chunk's global
// loads issue before the MFMA phase.
__global__ void __launch_bounds__(256)
gram_kernel(const float* __restrict__ W1, const float* __restrict__ b1,
            const float* __restrict__ W2, const float* __restrict__ b2,
            float* __restrict__ G) {
    __shared__ __align__(16) unsigned char smem[16384];  // bf16 [32][256] swizzled
    const int tid  = threadIdx.x;
    const int lane = tid & 63;
    const int w    = tid >> 6;      // wave 0..3
    const int r31  = lane & 31;     // fragment row (A.m = B.n)
    const int q    = lane >> 5;     // k half-select

    f32x16 acc;
    #pragma unroll
    for (int r = 0; r < 16; r++) acc[r] = 0.0f;

    float4 cur[8];
    auto issue = [&](int c) {
        Seg s = seg_of(W1, b1, W2, b2, c * 256);
        #pragma unroll
        for (int j = 0; j < 8; j++) {
            const int row = 8 * w + j;
            cur[j] = *reinterpret_cast<const float4*>(
                s.p + (size_t)row * s.stride + s.off + lane * 4);
        }
    };

    int c = blockIdx.x;
    if (c < NCHUNK) issue(c);
    for (; c < NCHUNK; c += gridDim.x) {
        // convert + swizzled ds_write: row (8w+j), lane writes 8B at col-byte 8*lane
        #pragma unroll
        for (int j = 0; j < 8; j++) {
            const int row = 8 * w + j;            // row & 7 == j
            uint32_t lo = ((uint32_t)(uint16_t)f2bf(cur[j].y) << 16) | (uint16_t)f2bf(cur[j].x);
            uint32_t hi = ((uint32_t)(uint16_t)f2bf(cur[j].w) << 16) | (uint16_t)f2bf(cur[j].z);
            uint2 pk = { lo, hi };
            const int boff = row * 512 + ((lane * 8) ^ (j << 4));
            *reinterpret_cast<uint2*>(smem + boff) = pk;
        }
        __syncthreads();
        const int cn = c + (int)gridDim.x;
        if (cn < NCHUNK) issue(cn);               // prefetch overlaps ds_read+MFMA
        // wave w consumes cols [w*64, w*64+64): 4 k-chunks of 16
        #pragma unroll
        for (int cc = 0; cc < 4; cc++) {
            const int colb = w * 128 + cc * 32 + q * 16;          // byte col
            const int boff = r31 * 512 + (colb ^ ((r31 & 7) << 4));
            bf16x8 f = *reinterpret_cast<const bf16x8*>(smem + boff);
            acc = __builtin_amdgcn_mfma_f32_32x32x16_bf16(f, f, acc, 0, 0, 0);
        }
        __syncthreads();
    }

    // Block-level reduction (reuse smem: 4 waves x f32[32][32] = 16KB exactly),
    // then ONE atomicAdd per G element per block (was 16 per lane per wave).
    float* red = reinterpret_cast<float*>(smem);
    #pragma unroll
    for (int r = 0; r < 16; r++) {
        const int orow = (r & 3) + 8 * (r >> 2) + 4 * q;  // m74/m101 D layout
        red[w * 1024 + orow * 32 + r31] = acc[r];
    }
    __syncthreads();
    #pragma unroll
    for (int e = 0; e < 4; e++) {
        const int idx = tid * 4 + e;
        const float v = red[idx] + red[1024 + idx] + red[2048 + idx] + red[3072 + idx];
        atomicAdd(&G[idx], v);
    }
}

// M_full = I + M': identity folded in so apply is a single 32x32 mat-vec with
// no runtime-indexed register array (rule #20).
// M_full[i][j] = delta_ij + (EPS/n)*K[i][j]*[j>=1] - delta_ij * 3*EPS*S_i/n
__global__ void computeM_kernel(const float* __restrict__ G, float* __restrict__ Mp) {
    __shared__ float Ks[32][32];
    const int t = threadIdx.x;           // <<<1,1024>>>
    const int i = t >> 5, j = t & 31;
    const float sqi = G[i * 33];
    const float sqj = G[j * 33];
    const float d2  = fmaxf(sqi + sqj - 2.0f * G[i * 32 + j], 0.0f);
    const float K   = expf(-0.5f * d2);
    Ks[i][j] = K;
    __syncthreads();
    float S = 0.0f;
    for (int m = 1; m < 32; m++) S += Ks[i][m];
    float v = (j >= 1) ? (EPS_F / 32.0f) * K : 0.0f;
    if (i == j) v += 1.0f - (3.0f * EPS_F / 32.0f) * S;
    Mp[i * 32 + j] = v;
}

// out = M_full @ theta, pure f32 VALU. Each lane owns 4 consecutive columns
// (float4 loads AND stores, 1KB/wave-instr coalesced); all 32 particle rows
// live in registers; Mp rows are wave-uniform scalar loads.
__global__ void __launch_bounds__(256)
apply_kernel(const float* __restrict__ W1, const float* __restrict__ b1,
             const float* __restrict__ W2, const float* __restrict__ b2,
             const float* __restrict__ Mp, float* __restrict__ out) {
    const int lane   = threadIdx.x & 63;
    const int wave   = (blockIdx.x * 256 + threadIdx.x) >> 6;
    const int nwaves = gridDim.x * 4;

    for (int ch = wave; ch < NCHUNK; ch += nwaves) {
        const int pbase = ch * 256;                  // 256-col chunk, one segment
        Seg s = seg_of(W1, b1, W2, b2, pbase);
        const float* sp = s.p + s.off + lane * 4;
        const size_t str = (size_t)s.stride;

        float4 th[32];
        #pragma unroll
        for (int j = 0; j < 32; ++j)
            th[j] = *reinterpret_cast<const float4*>(sp + j * str);

        float* op = out + (size_t)pbase + lane * 4;
        #pragma unroll 1   // keep i-loop rolled: th[] stays the only big reg block
        for (int i = 0; i < 32; ++i) {
            const float* mrow = Mp + i * 32;         // uniform address -> s_load
            float ax = 0.f, ay = 0.f, az = 0.f, aw = 0.f;
            #pragma unroll
            for (int j = 0; j < 32; ++j) {
                const float m = mrow[j];
                ax = fmaf(m, th[j].x, ax);
                ay = fmaf(m, th[j].y, ay);
                az = fmaf(m, th[j].z, az);
                aw = fmaf(m, th[j].w, aw);
            }
            float4 o = { ax, ay, az, aw };
            *reinterpret_cast<float4*>(op + (size_t)i * P_TOT) = o;
        }
    }
}

extern "C" void kernel_launch(void* const* d_in, const int* in_sizes, int n_in,
                              void* d_out, int out_size, void* d_ws, size_t ws_size,
                              hipStream_t stream) {
    const float* W1 = (const float*)d_in[0];
    const float* b1 = (const float*)d_in[1];
    const float* W2 = (const float*)d_in[2];
    const float* b2 = (const float*)d_in[3];
    // d_in[4] (X) and d_in[5] (y) are unused by the reference computation.
    float* out = (float*)d_out;
    float* G   = (float*)d_ws;          // 1024 floats
    float* Mp  = G + 1024;              // 1024 floats

    zero_kernel<<<1, 1024, 0, stream>>>(G);
    gram_kernel<<<1024, 256, 0, stream>>>(W1, b1, W2, b2, G);
    computeM_kernel<<<1, 1024, 0, stream>>>(G, Mp);
    apply_kernel<<<1024, 256, 0, stream>>>(W1, b1, W2, b2, Mp, out);
}